// Round 19
// baseline (53.872 us; speedup 1.0000x reference)
//
#include <hip/hip_runtime.h>

typedef short short8 __attribute__((ext_vector_type(8)));
typedef float f32x16 __attribute__((ext_vector_type(16)));

#define NPTS 4096
#define NB   32
#define NT   (NPTS / 32)       // 128 scan iterations (full B per block)
#define SCALE (1.0f / 131072.0f)   // 1/(NB*NPTS)

// ---- bf16 split helpers (round-to-nearest-even) ----
__device__ inline unsigned short bf16_rne(float v) {
    unsigned u = __float_as_uint(v);
    unsigned r = u + 0x7FFFu + ((u >> 16) & 1u);
    return (unsigned short)(r >> 16);
}
__device__ inline float bf16_to_f(unsigned short h) {
    return __uint_as_float(((unsigned)h) << 16);
}
__device__ inline void bf_split(float v, unsigned short& h, unsigned short& l) {
    h = bf16_rne(v);
    l = bf16_rne(v - bf16_to_f(h));
}

// ---- pre-pass: pack records; zero d_out ----
__global__ __launch_bounds__(256) void pack_kernel(
    const float* __restrict__ points, const float* __restrict__ gts,
    unsigned short* __restrict__ pk, float* __restrict__ outp)
{
    const int tid = blockIdx.x * 256 + threadIdx.x;   // 0 .. 262143
    if (tid < 3) outp[tid] = 0.0f;                    // reduce accumulates
    const int c   = tid >> 17;                        // cloud
    const int rem = tid & 131071;                     // b*4096 + j
    const float* src = (c ? gts : points) + (size_t)rem * 3;
    const float x = src[0], y = src[1], z = src[2];
    const float hb = x * x + y * y + z * z;
    unsigned short xh, xl, yh, yl, zh, zl, hh, hl;
    bf_split(x, xh, xl); bf_split(y, yh, yl);
    bf_split(z, zh, zl); bf_split(hb, hh, hl);
    const unsigned short ONE = 0x3F80;
    unsigned short r[16] = { xh, yh, zh, ONE, hh,
                             xl, yl, zl, 0,   hl,
                             xh, yh, zh, ONE, hh, 0 };
    int4* dst = (int4*)(pk + (size_t)tid * 16);
    int4 w0, w1;
    w0.x = r[0] | (r[1] << 16);  w0.y = r[2]  | (r[3]  << 16);
    w0.z = r[4] | (r[5] << 16);  w0.w = r[6]  | (r[7]  << 16);
    w1.x = r[8] | (r[9] << 16);  w1.y = r[10] | (r[11] << 16);
    w1.z = r[12]| (r[13]<< 16);  w1.w = r[14] | (r[15] << 16);
    dst[0] = w0; dst[1] = w1;
}

// ---- main: S=1, full-B MFMA scan; plain-store mins ----
__global__ __launch_bounds__(256, 4) void chamfer_main(
    const float* __restrict__ points, const float* __restrict__ gts,
    const unsigned short* __restrict__ pk, float* __restrict__ mins)
{
    const int d      = blockIdx.x;        // 0..2047
    const int group  = d & 63;            // (dir,b) — members share XCD (mod 8)
    const int member = d >> 6;            // A-chunk 0..31 (128 points each)
    const int dir = group >> 5;
    const int b   = group & 31;

    const float* Ab = (dir ? gts : points) + (size_t)b * NPTS * 3;
    const int w = threadIdx.x >> 6, l = threadIdx.x & 63;
    const int half = l >> 5, c = l & 31;

    // pinned fragment (mfma B operand) — packing identical to verified R5..R18
    short8 af;
    {
        const int i = member * 128 + w * 32 + c;
        const float ax = Ab[i * 3 + 0], ay = Ab[i * 3 + 1], az = Ab[i * 3 + 2];
        const float ha = ax * ax + ay * ay + az * az;
        unsigned short xh, xl, yh, yl, zh, zl, hh, hl;
        bf_split(-2.f * ax, xh, xl);
        bf_split(-2.f * ay, yh, yl);
        bf_split(-2.f * az, zh, zl);
        bf_split(ha, hh, hl);
        const unsigned short ONE = 0x3F80;
        if (half == 0) {
            af[0]=(short)xh; af[1]=(short)yh; af[2]=(short)zh; af[3]=(short)hh;
            af[4]=(short)ONE; af[5]=(short)xh; af[6]=(short)yh; af[7]=(short)zh;
        } else {
            af[0]=(short)hh; af[1]=(short)ONE; af[2]=(short)xl; af[3]=(short)yl;
            af[4]=(short)zl; af[5]=(short)hl; af[6]=0; af[7]=0;
        }
    }

    // streamed records: the FULL B cloud for this (dir,b)
    const unsigned short* rec =
        pk + (((size_t)(dir ^ 1) * NB + b) * NPTS + (size_t)c) * 16 + half * 8;

    f32x16 zc;
    #pragma unroll
    for (int q = 0; q < 16; ++q) zc[q] = 0.f;

    float mm = 1e30f;

#define BODY(REG)                                                              \
    {                                                                          \
        const f32x16 a =                                                       \
            __builtin_amdgcn_mfma_f32_32x32x16_bf16((REG), af, zc, 0, 0, 0);   \
        const float t0 = fminf(fminf(a[0],  a[1]),  a[2]);                     \
        const float t1 = fminf(fminf(a[3],  a[4]),  a[5]);                     \
        const float t2 = fminf(fminf(a[6],  a[7]),  a[8]);                     \
        const float t3 = fminf(fminf(a[9],  a[10]), a[11]);                    \
        const float t4 = fminf(fminf(a[12], a[13]), a[14]);                    \
        const float u0 = fminf(fminf(t0, t1), t2);                             \
        const float u1 = fminf(fminf(t3, t4), a[15]);                          \
        mm = fminf(fminf(mm, u0), u1);                                         \
    }

    short8 cur = *(const short8*)(rec);

    // 2-iteration scheduling window: 2 MFMAs + 2 trees between fences.
    #pragma unroll 1
    for (int t = 0; t + 2 < NT; t += 2) {
        const short8 n0 = *(const short8*)(rec + (size_t)(t + 1) * 512);
        const short8 n1 = *(const short8*)(rec + (size_t)(t + 2) * 512);
        BODY(cur)
        BODY(n0)
        __builtin_amdgcn_sched_barrier(0);   // cap window (spill guard)
        cur = n1;
    }
    {   // peeled tail: iterations NT-2, NT-1
        const short8 n0 = *(const short8*)(rec + (size_t)(NT - 1) * 512);
        BODY(cur)
        BODY(n0)
    }
#undef BODY

    // combine halves, clamp, plain store (single writer per a-point)
    {
        float v = fminf(mm, __shfl_xor(mm, 32));
        v = fmaxf(v, 0.f);
        if (half == 0) {
            const int ap = member * 128 + w * 32 + c;
            mins[(size_t)group * NPTS + ap] = v;
        }
    }
}

// ---- pass 2: one block per (dir,b) group; 128 total d_out atomics ----
__global__ __launch_bounds__(256) void reduce_kernel(
    const float* __restrict__ mins, float* __restrict__ outp)
{
    const int group = blockIdx.x;          // 0..63
    const int dir   = group >> 5;
    const float* gm = mins + (size_t)group * NPTS;

    float local = 0.f;
    #pragma unroll
    for (int i = 0; i < NPTS / 256; ++i)
        local += sqrtf(gm[threadIdx.x + i * 256]);

    for (int off = 32; off > 0; off >>= 1)
        local += __shfl_down(local, off);
    __shared__ float wsum[4];
    const int w = threadIdx.x >> 6, l = threadIdx.x & 63;
    if (l == 0) wsum[w] = local;
    __syncthreads();
    if (threadIdx.x == 0) {
        const float s = (wsum[0] + wsum[1] + wsum[2] + wsum[3]) * SCALE;
        atomicAdd(&outp[0], s);          // p2g + g2p
        atomicAdd(&outp[1 + dir], s);    // out[1]=p2g, out[2]=g2p
    }
}

extern "C" void kernel_launch(void* const* d_in, const int* in_sizes, int n_in,
                              void* d_out, int out_size, void* d_ws, size_t ws_size,
                              hipStream_t stream) {
    const float* points = (const float*)d_in[0];   // [32][4096][3]
    const float* gts    = (const float*)d_in[1];   // [32][4096][3]
    float* outp = (float*)d_out;

    unsigned short* packed = (unsigned short*)((char*)d_ws + 64);   // 8 MB
    float* mins = (float*)((char*)d_ws + 64 + 8388608);             // 1 MB

    pack_kernel<<<1024, 256, 0, stream>>>(points, gts, packed, outp);
    chamfer_main<<<2048, 256, 0, stream>>>(points, gts, packed, mins);
    reduce_kernel<<<64, 256, 0, stream>>>(mins, outp);
}

// Round 20
// 46.272 us; speedup vs baseline: 1.1643x; 1.1643x over previous
//
#include <hip/hip_runtime.h>

typedef short short8 __attribute__((ext_vector_type(8)));
typedef float f32x16 __attribute__((ext_vector_type(16)));

#define NPTS 4096
#define NB   32
#define S    2        // pinned 32-point strips per wave
#define NT   (NPTS / 32)       // 128 scan iterations (full B per block)
#define SCALE (1.0f / 131072.0f)   // 1/(NB*NPTS)

// ---- bf16 split helpers (round-to-nearest-even) ----
__device__ inline unsigned short bf16_rne(float v) {
    unsigned u = __float_as_uint(v);
    unsigned r = u + 0x7FFFu + ((u >> 16) & 1u);
    return (unsigned short)(r >> 16);
}
__device__ inline float bf16_to_f(unsigned short h) {
    return __uint_as_float(((unsigned)h) << 16);
}
__device__ inline void bf_split(float v, unsigned short& h, unsigned short& l) {
    h = bf16_rne(v);
    l = bf16_rne(v - bf16_to_f(h));
}

// ---- pre-pass: pack records; zero d_out ----
__global__ __launch_bounds__(256) void pack_kernel(
    const float* __restrict__ points, const float* __restrict__ gts,
    unsigned short* __restrict__ pk, float* __restrict__ outp)
{
    const int tid = blockIdx.x * 256 + threadIdx.x;   // 0 .. 262143
    if (tid < 3) outp[tid] = 0.0f;                    // reduce accumulates
    const int c   = tid >> 17;                        // cloud
    const int rem = tid & 131071;                     // b*4096 + j
    const float* src = (c ? gts : points) + (size_t)rem * 3;
    const float x = src[0], y = src[1], z = src[2];
    const float hb = x * x + y * y + z * z;
    unsigned short xh, xl, yh, yl, zh, zl, hh, hl;
    bf_split(x, xh, xl); bf_split(y, yh, yl);
    bf_split(z, zh, zl); bf_split(hb, hh, hl);
    const unsigned short ONE = 0x3F80;
    unsigned short r[16] = { xh, yh, zh, ONE, hh,
                             xl, yl, zl, 0,   hl,
                             xh, yh, zh, ONE, hh, 0 };
    int4* dst = (int4*)(pk + (size_t)tid * 16);
    int4 w0, w1;
    w0.x = r[0] | (r[1] << 16);  w0.y = r[2]  | (r[3]  << 16);
    w0.z = r[4] | (r[5] << 16);  w0.w = r[6]  | (r[7]  << 16);
    w1.x = r[8] | (r[9] << 16);  w1.y = r[10] | (r[11] << 16);
    w1.z = r[12]| (r[13]<< 16);  w1.w = r[14] | (r[15] << 16);
    dst[0] = w0; dst[1] = w1;
}

// ---- main: full-B MFMA scan, 3-deep record prefetch pipeline ----
__global__ __launch_bounds__(256, 4) void chamfer_main(
    const float* __restrict__ points, const float* __restrict__ gts,
    const unsigned short* __restrict__ pk, float* __restrict__ mins)
{
    const int d      = blockIdx.x;        // 0..1023
    const int group  = d & 63;            // (dir,b) — members share XCD (mod 8)
    const int member = d >> 6;            // A-chunk 0..15 (256 points each)
    const int dir = group >> 5;
    const int b   = group & 31;

    const float* Ab = (dir ? gts : points) + (size_t)b * NPTS * 3;
    const int w = threadIdx.x >> 6, l = threadIdx.x & 63;
    const int half = l >> 5, c = l & 31;

    // pinned fragments (mfma B operand) — packing identical to verified R5..R18
    short8 af[S];
    #pragma unroll
    for (int s = 0; s < S; ++s) {
        const int i = member * 256 + w * 64 + s * 32 + c;
        const float ax = Ab[i * 3 + 0], ay = Ab[i * 3 + 1], az = Ab[i * 3 + 2];
        const float ha = ax * ax + ay * ay + az * az;
        unsigned short xh, xl, yh, yl, zh, zl, hh, hl;
        bf_split(-2.f * ax, xh, xl);
        bf_split(-2.f * ay, yh, yl);
        bf_split(-2.f * az, zh, zl);
        bf_split(ha, hh, hl);
        const unsigned short ONE = 0x3F80;
        short8 f;
        if (half == 0) {
            f[0]=(short)xh; f[1]=(short)yh; f[2]=(short)zh; f[3]=(short)hh;
            f[4]=(short)ONE; f[5]=(short)xh; f[6]=(short)yh; f[7]=(short)zh;
        } else {
            f[0]=(short)hh; f[1]=(short)ONE; f[2]=(short)xl; f[3]=(short)yl;
            f[4]=(short)zl; f[5]=(short)hl; f[6]=0; f[7]=0;
        }
        af[s] = f;
    }

    // streamed records: the FULL B cloud for this (dir,b)
    const unsigned short* rec =
        pk + (((size_t)(dir ^ 1) * NB + b) * NPTS + (size_t)c) * 16 + half * 8;

    f32x16 zc;
    #pragma unroll
    for (int q = 0; q < 16; ++q) zc[q] = 0.f;

    float mm[S] = {1e30f, 1e30f};

#define BODY(REG)                                                              \
    {                                                                          \
        _Pragma("unroll")                                                      \
        for (int s = 0; s < S; ++s) {                                          \
            const f32x16 a =                                                   \
                __builtin_amdgcn_mfma_f32_32x32x16_bf16((REG), af[s], zc, 0, 0, 0); \
            const float t0 = fminf(fminf(a[0],  a[1]),  a[2]);                 \
            const float t1 = fminf(fminf(a[3],  a[4]),  a[5]);                 \
            const float t2 = fminf(fminf(a[6],  a[7]),  a[8]);                 \
            const float t3 = fminf(fminf(a[9],  a[10]), a[11]);                \
            const float t4 = fminf(fminf(a[12], a[13]), a[14]);                \
            const float u0 = fminf(fminf(t0, t1), t2);                         \
            const float u1 = fminf(fminf(t3, t4), a[15]);                      \
            mm[s] = fminf(fminf(mm[s], u0), u1);                               \
        }                                                                      \
    }

    // 3-deep record pipeline: every record is ~3 units (~280 cyc) in flight
    // before its MFMA consumes it — covers L2 latency at 4 waves/SIMD.
    short8 c0 = *(const short8*)(rec);
    short8 c1 = *(const short8*)(rec + 512);
    short8 c2 = *(const short8*)(rec + 1024);

    // unroll 4: the 3-tuple rotation becomes pure SSA renaming (no movs);
    // per-unit sched_barrier keeps <=2 live accs (spill guard, R16-verified).
    #pragma unroll 4
    for (int t = 0; t < NT; ++t) {
        const int tn = (t + 3 < NT) ? (t + 3) : (NT - 1);
        const short8 nx = *(const short8*)(rec + (size_t)tn * 512);
        BODY(c0)
        __builtin_amdgcn_sched_barrier(0);
        c0 = c1; c1 = c2; c2 = nx;
    }
#undef BODY

    // combine halves, clamp, plain store (single writer per a-point)
    #pragma unroll
    for (int s = 0; s < S; ++s) {
        float v = fminf(mm[s], __shfl_xor(mm[s], 32));
        v = fmaxf(v, 0.f);
        if (half == 0) {
            const int ap = member * 256 + w * 64 + s * 32 + c;
            mins[(size_t)group * NPTS + ap] = v;
        }
    }
}

// ---- pass 2: one block per (dir,b) group; 128 total d_out atomics ----
__global__ __launch_bounds__(256) void reduce_kernel(
    const float* __restrict__ mins, float* __restrict__ outp)
{
    const int group = blockIdx.x;          // 0..63
    const int dir   = group >> 5;
    const float* gm = mins + (size_t)group * NPTS;

    float local = 0.f;
    #pragma unroll
    for (int i = 0; i < NPTS / 256; ++i)
        local += sqrtf(gm[threadIdx.x + i * 256]);

    for (int off = 32; off > 0; off >>= 1)
        local += __shfl_down(local, off);
    __shared__ float wsum[4];
    const int w = threadIdx.x >> 6, l = threadIdx.x & 63;
    if (l == 0) wsum[w] = local;
    __syncthreads();
    if (threadIdx.x == 0) {
        const float s = (wsum[0] + wsum[1] + wsum[2] + wsum[3]) * SCALE;
        atomicAdd(&outp[0], s);          // p2g + g2p
        atomicAdd(&outp[1 + dir], s);    // out[1]=p2g, out[2]=g2p
    }
}

extern "C" void kernel_launch(void* const* d_in, const int* in_sizes, int n_in,
                              void* d_out, int out_size, void* d_ws, size_t ws_size,
                              hipStream_t stream) {
    const float* points = (const float*)d_in[0];   // [32][4096][3]
    const float* gts    = (const float*)d_in[1];   // [32][4096][3]
    float* outp = (float*)d_out;

    unsigned short* packed = (unsigned short*)((char*)d_ws + 64);   // 8 MB
    float* mins = (float*)((char*)d_ws + 64 + 8388608);             // 1 MB

    pack_kernel<<<1024, 256, 0, stream>>>(points, gts, packed, outp);
    chamfer_main<<<1024, 256, 0, stream>>>(points, gts, packed, mins);
    reduce_kernel<<<64, 256, 0, stream>>>(mins, outp);
}